// Round 6
// baseline (458.893 us; speedup 1.0000x reference)
//
#include <hip/hip_runtime.h>

#define T_STEPS 512
#define BT 8           // batches per block (half a 16-col MFMA tile; cols 8-15 garbage)
#define XSTRIDE 524    // padded x row stride (floats)
#define HSTRIDE 72     // padded h row stride (shorts); 144B rows, 16B aligned

typedef __attribute__((ext_vector_type(8))) short bf16x8;
typedef __attribute__((ext_vector_type(4))) float f32x4;

__device__ __forceinline__ short f2bf(float f) {
    union { float f; unsigned u; } v; v.f = f;
    unsigned r = v.u + 0x7fffu + ((v.u >> 16) & 1u);   // RNE
    return (short)(r >> 16);
}
__device__ __forceinline__ float bf2f(short s) {
    union { float f; unsigned u; } v;
    v.u = ((unsigned)(unsigned short)s) << 16;
    return v.f;
}
__device__ __forceinline__ float ubits(unsigned u) {
    union { unsigned u; float f; } v; v.u = u; return v.f;
}
__device__ __forceinline__ float exp2_fast(float x) {
#if __has_builtin(__builtin_amdgcn_exp2f)
    return __builtin_amdgcn_exp2f(x);
#else
    return __expf(x * 0.69314718056f);
#endif
}

#define L2E 1.44269504089f   // log2(e)
#define C2  2.88539008178f   // 2*log2(e)

__global__ __launch_bounds__(256, 2) void lstm_persist(
    const float* __restrict__ x,      // [B, T] (IN=1 folded)
    const float* __restrict__ W_ih,   // [256]
    const float* __restrict__ W_hh,   // [256,64]
    const float* __restrict__ b_ih,   // [256]
    const float* __restrict__ b_hh,   // [256]
    const float* __restrict__ W_fc,   // [64]
    const float* __restrict__ b_fc,   // [1]
    float* __restrict__ out)          // [B]
{
    __shared__ __align__(16) float x_lds[BT * XSTRIDE];      // 16.8 KB
    __shared__ __align__(16) short hbuf[2][2][BT][HSTRIDE];  // 4.6 KB [buf][hi/lo][b][k]

    const int tid  = threadIdx.x;
    const int wave = tid >> 6;     // 0..3  -> k-slice: k in [16w, 16w+16)
    const int lane = tid & 63;
    const int l15  = lane & 15;    // MFMA output col
    const int bl   = l15 & 7;      // batch index (cols 8-15 mirror 0-7)
    const int half = l15 >> 3;     // 0: cells r=0,1   1: cells r=2,3 (via shfl)
    const int quad = lane >> 4;    // 0..3
    const int b0   = blockIdx.x * BT;

    // ---- stage x[b0..b0+7][0..511] into LDS (coalesced float4) ----
    {
        const float* xg = x + (size_t)b0 * T_STEPS;
        #pragma unroll
        for (int i = 0; i < 4; ++i) {
            int f4 = tid + i * 256;        // 0..1023 float4 chunks
            int b  = f4 >> 7;              // 128 float4 per row
            int t4 = f4 & 127;
            float4 v = reinterpret_cast<const float4*>(xg + (size_t)b * T_STEPS)[t4];
            reinterpret_cast<float4*>(&x_lds[b * XSTRIDE + t4 * 4])[0] = v;
        }
    }
    // ---- zero h buffer 0 (hi+lo) ----
    {
        short* p = &hbuf[0][0][0][0];
        for (int i = tid; i < 2 * BT * HSTRIDE; i += 256) p[i] = 0;
    }

    // ---- per-lane resident W_hh fragments (split bf16 of SCALED weights) ----
    // Gate scales folded in: i,f,o rows by -log2e; g rows by -2*log2e.
    // A-frag rows are GATE rows (all 16 valid regardless of BT).
    const float scg[4] = { -L2E, -L2E, -C2, -L2E };
    bf16x8 Whi[4][2], Wlo[4][2];
    f32x4 bias4[4], wih4[4];
    #pragma unroll
    for (int g = 0; g < 4; ++g) {
        int na = g * 64 + wave * 16 + l15;
        #pragma unroll
        for (int kh = 0; kh < 2; ++kh) {
            const float* wr = W_hh + na * 64 + kh * 32 + quad * 8;
            bf16x8 hi, lo;
            #pragma unroll
            for (int j = 0; j < 8; ++j) {
                float w = wr[j] * scg[g];
                short h16 = f2bf(w);
                hi[j] = h16;
                lo[j] = f2bf(w - bf2f(h16));
            }
            Whi[g][kh] = hi;
            Wlo[g][kh] = lo;
        }
        // D layout: col = l15, row = quad*4 + r.
        // Cell ownership after shfl: lane handles batch=bl, k = wave*16+quad*4+2*half+{0,1}
        #pragma unroll
        for (int r = 0; r < 4; ++r) {
            int n = g * 64 + wave * 16 + quad * 4 + r;
            bias4[g][r] = scg[g] * (b_ih[n] + b_hh[n]);
            wih4[g][r]  = scg[g] * W_ih[n];
        }
    }

    float ct0 = 0.f, ct1 = 0.f;    // cell state (2 cells/lane), scaled by 2*log2e
    const int hoff = bl * HSTRIDE + quad * 8;                     // B-frag read (dup over half -> broadcast)
    const int woff32 = bl * 36 + wave * 8 + quad * 2 + half;      // u32 index: shorts (b*72 + w*16+q*4+2h)/2
    const float* xrow = &x_lds[bl * XSTRIDE];

    __syncthreads();

    // init for t=0 precomputed (x is h-independent): un-roots MFMA chain from x load
    f32x4 iv[4];
    {
        float xv = xrow[0];
        f32x4 xv4 = {xv, xv, xv, xv};
        #pragma unroll
        for (int g = 0; g < 4; ++g)
            iv[g] = __builtin_elementwise_fma(wih4[g], xv4, bias4[g]);
    }

    #pragma unroll 2
    for (int t = 0; t < T_STEPS; ++t) {
        const int rb = t & 1, wb = rb ^ 1;
        const short* hhi = &hbuf[rb][0][0][0];
        const short* hlo = &hbuf[rb][1][0][0];

        // issue all LDS reads up front (h fragments + next-step x)
        bf16x8 bhi0 = *reinterpret_cast<const bf16x8*>(hhi + hoff);
        bf16x8 bhi1 = *reinterpret_cast<const bf16x8*>(hhi + hoff + 32);
        bf16x8 blo0 = *reinterpret_cast<const bf16x8*>(hlo + hoff);
        bf16x8 blo1 = *reinterpret_cast<const bf16x8*>(hlo + hoff + 32);
        float xn = xrow[t + 1];   // t=511 reads in-bounds pad; result unused

        // verified 6-term order, C-op seeded directly from prefetched iv
        f32x4 acc[4];
        #pragma unroll
        for (int g = 0; g < 4; ++g) {
            acc[g] = __builtin_amdgcn_mfma_f32_16x16x32_bf16(Whi[g][0], bhi0, iv[g], 0, 0, 0);
            acc[g] = __builtin_amdgcn_mfma_f32_16x16x32_bf16(Whi[g][1], bhi1, acc[g], 0, 0, 0);
            acc[g] = __builtin_amdgcn_mfma_f32_16x16x32_bf16(Whi[g][0], blo0, acc[g], 0, 0, 0);
            acc[g] = __builtin_amdgcn_mfma_f32_16x16x32_bf16(Whi[g][1], blo1, acc[g], 0, 0, 0);
            acc[g] = __builtin_amdgcn_mfma_f32_16x16x32_bf16(Wlo[g][0], bhi0, acc[g], 0, 0, 0);
            acc[g] = __builtin_amdgcn_mfma_f32_16x16x32_bf16(Wlo[g][1], bhi1, acc[g], 0, 0, 0);
        }

        // next-step iv prefetch issues in the MFMA-latency shadow (packed fp32)
        {
            f32x4 xn4 = {xn, xn, xn, xn};
            #pragma unroll
            for (int g = 0; g < 4; ++g)
                iv[g] = __builtin_elementwise_fma(wih4[g], xn4, bias4[g]);
        }

        // redistribute: lanes l15>=8 take partner's r=2,3 cells -> 2 cells/lane
        float av[4][2];
        #pragma unroll
        for (int g = 0; g < 4; ++g) {
            float s2 = __shfl_xor(acc[g][2], 8);
            float s3 = __shfl_xor(acc[g][3], 8);
            av[g][0] = half ? s2 : acc[g][0];
            av[g][1] = half ? s3 : acc[g][1];
        }

        // activations in scaled domain (2 cells): acc IS the exp2 argument.
        // signed-eg (safe range); clamped signed-ec (exact saturation).
        float hv0, hv1;
        {
            float ei = exp2_fast(av[0][0]);
            float ef = exp2_fast(av[1][0]);
            float eg = exp2_fast(av[2][0]);
            float eo = exp2_fast(av[3][0]);
            float Ai = 1.0f + ei, Af = 1.0f + ef, Ag = 1.0f + eg, Ao = 1.0f + eo;
            float P   = Ai * Ag;
            float rP  = __builtin_amdgcn_rcpf(P * Af);
            float tg  = fmaf(-C2, eg, C2);
            float num = fmaf(ct0, P, tg * Af);
            float cn  = num * rP;
            ct0 = cn;
            float ec = exp2_fast(fminf(-cn, 40.0f));
            hv0 = (1.0f - ec) * __builtin_amdgcn_rcpf(Ao * (1.0f + ec));
        }
        {
            float ei = exp2_fast(av[0][1]);
            float ef = exp2_fast(av[1][1]);
            float eg = exp2_fast(av[2][1]);
            float eo = exp2_fast(av[3][1]);
            float Ai = 1.0f + ei, Af = 1.0f + ef, Ag = 1.0f + eg, Ao = 1.0f + eo;
            float P   = Ai * Ag;
            float rP  = __builtin_amdgcn_rcpf(P * Af);
            float tg  = fmaf(-C2, eg, C2);
            float num = fmaf(ct1, P, tg * Af);
            float cn  = num * rP;
            ct1 = cn;
            float ec = exp2_fast(fminf(-cn, 40.0f));
            hv1 = (1.0f - ec) * __builtin_amdgcn_rcpf(Ao * (1.0f + ec));
        }

        // bf16 pack (HW RNE) + exact lo residuals; 1 hi + 1 lo ds_write_b32 per lane
        unsigned* whi = reinterpret_cast<unsigned*>(&hbuf[wb][0][0][0]);
        unsigned* wlo = reinterpret_cast<unsigned*>(&hbuf[wb][1][0][0]);
        unsigned hi01, lo01;
        asm("v_cvt_pk_bf16_f32 %0, %1, %2" : "=v"(hi01) : "v"(hv0), "v"(hv1));
        whi[woff32] = hi01;
        float l0f = hv0 - ubits(hi01 << 16);
        float l1f = hv1 - ubits(hi01 & 0xffff0000u);
        asm("v_cvt_pk_bf16_f32 %0, %1, %2" : "=v"(lo01) : "v"(l0f), "v"(l1f));
        wlo[woff32] = lo01;

        __syncthreads();   // h(t+1) visible; also protects next step's overwrite of rb
    }

    // ---- final FC: out[b] = sum_k h[b][k]*W_fc[k] + b_fc  (h = buf 0 after t=511) ----
    if (tid < BT) {
        int b = tid;
        float s = b_fc[0];
        #pragma unroll 4
        for (int k = 0; k < 64; ++k) {
            float hv = bf2f(hbuf[0][0][b][k]) + bf2f(hbuf[0][1][b][k]);
            s += hv * W_fc[k];
        }
        out[b0 + b] = s;
    }
}

extern "C" void kernel_launch(void* const* d_in, const int* in_sizes, int n_in,
                              void* d_out, int out_size, void* d_ws, size_t ws_size,
                              hipStream_t stream) {
    const float* x    = (const float*)d_in[0];
    const float* W_ih = (const float*)d_in[1];
    const float* W_hh = (const float*)d_in[2];
    const float* b_ih = (const float*)d_in[3];
    const float* b_hh = (const float*)d_in[4];
    const float* W_fc = (const float*)d_in[5];
    const float* b_fc = (const float*)d_in[6];
    float* out = (float*)d_out;
    const int B = in_sizes[0] / T_STEPS;   // 4096
    lstm_persist<<<dim3(B / BT), dim3(256), 0, stream>>>(
        x, W_ih, W_hh, b_ih, b_hh, W_fc, b_fc, out);
}

// Round 7
// 338.508 us; speedup vs baseline: 1.3556x; 1.3556x over previous
//
#include <hip/hip_runtime.h>

#define T_STEPS 512
#define BT 16          // batches per block (one 16-col MFMA tile, batch = l15)
#define XSTRIDE 524    // padded x row stride (floats)
#define HS2 136        // shorts per h row: 128 virtual-K slots + 8 pad (272B, 16B-aligned)

typedef __attribute__((ext_vector_type(8))) short bf16x8;
typedef __attribute__((ext_vector_type(4))) float f32x4;
typedef __attribute__((ext_vector_type(4))) unsigned u32x4;

__device__ __forceinline__ short f2bf(float f) {
    union { float f; unsigned u; } v; v.f = f;
    unsigned r = v.u + 0x7fffu + ((v.u >> 16) & 1u);   // RNE
    return (short)(r >> 16);
}
__device__ __forceinline__ float bf2f(short s) {
    union { float f; unsigned u; } v;
    v.u = ((unsigned)(unsigned short)s) << 16;
    return v.f;
}
__device__ __forceinline__ float ubits(unsigned u) {
    union { unsigned u; float f; } v; v.u = u; return v.f;
}
__device__ __forceinline__ float exp2_fast(float x) {
#if __has_builtin(__builtin_amdgcn_exp2f)
    return __builtin_amdgcn_exp2f(x);
#else
    return __expf(x * 0.69314718056f);
#endif
}

#define L2E 1.44269504089f   // log2(e)
#define C2  2.88539008178f   // 2*log2(e)

__global__ __launch_bounds__(256, 1) void lstm_persist(
    const float* __restrict__ x,      // [B, T] (IN=1 folded)
    const float* __restrict__ W_ih,   // [256]
    const float* __restrict__ W_hh,   // [256,64]
    const float* __restrict__ b_ih,   // [256]
    const float* __restrict__ b_hh,   // [256]
    const float* __restrict__ W_fc,   // [64]
    const float* __restrict__ b_fc,   // [1]
    float* __restrict__ out)          // [B]
{
    __shared__ __align__(16) float x_lds[BT * XSTRIDE];    // 33.5 KB
    __shared__ __align__(16) short hbuf[2][BT][HS2];       // 8.7 KB, interleaved [hi x4 | lo x4] per k-quad

    const int tid  = threadIdx.x;
    const int wave = tid >> 6;     // 0..3  -> k-slice: k in [16w, 16w+16)
    const int lane = tid & 63;
    const int l15  = lane & 15;    // batch index (output col)
    const int quad = lane >> 4;    // 0..3
    const int b0   = blockIdx.x * BT;

    // ---- stage x[b0..b0+15][0..511] into LDS (coalesced float4) ----
    {
        const float* xg = x + (size_t)b0 * T_STEPS;
        #pragma unroll
        for (int i = 0; i < 8; ++i) {
            int f4 = tid + i * 256;        // 0..2047 float4 chunks
            int b  = f4 >> 7;              // 128 float4 per row
            int t4 = f4 & 127;
            float4 v = reinterpret_cast<const float4*>(xg + (size_t)b * T_STEPS)[t4];
            reinterpret_cast<float4*>(&x_lds[b * XSTRIDE + t4 * 4])[0] = v;
        }
    }
    // ---- zero h buffer 0 ----
    {
        short* p = &hbuf[0][0][0];
        for (int i = tid; i < BT * HS2; i += 256) p[i] = 0;
    }

    // ---- per-lane resident W fragments: duplicated-Whi virtual-K layout ----
    // Virtual-K slot s (0..31) of MFMA m: k(s) = m*16 + (s>>3)*4 + (s&3),
    // part = hi if (s&7)<4 else lo. A-value = Whi_scaled[gate_row][k(s)] for BOTH
    // parts -> gates = sum Whi*(h_hi + h_lo) = sum Whi*h (exact in h, bf16 in W).
    // Gate scales folded in: i,f,o rows by -log2e; g rows by -2*log2e.
    const float scg[4] = { -L2E, -L2E, -C2, -L2E };
    bf16x8 Wv[4][4];               // [gate][m]
    f32x4 bias4[4], wih4[4];
    #pragma unroll
    for (int g = 0; g < 4; ++g) {
        int na = g * 64 + wave * 16 + l15;
        #pragma unroll
        for (int m = 0; m < 4; ++m) {
            const float* wr = W_hh + na * 64 + m * 16 + quad * 4;
            bf16x8 a;
            #pragma unroll
            for (int jj = 0; jj < 4; ++jj) {
                short h16 = f2bf(wr[jj] * scg[g]);
                a[jj]     = h16;
                a[jj + 4] = h16;
            }
            Wv[g][m] = a;
        }
        // D layout: col = l15 (batch), row = quad*4 + r ->
        // lane owns gate g, k_hidden = wave*16 + quad*4 + r, batch l15.
        #pragma unroll
        for (int r = 0; r < 4; ++r) {
            int n = g * 64 + wave * 16 + quad * 4 + r;
            bias4[g][r] = scg[g] * (b_ih[n] + b_hh[n]);
            wih4[g][r]  = scg[g] * W_ih[n];
        }
    }

    f32x4 ct4 = {0.f, 0.f, 0.f, 0.f};   // cell state, scaled by 2*log2e
    const int hoff = l15 * HS2 + quad * 8;                 // B-frag base (shorts)
    const int w32  = l15 * (HS2 / 2) + (wave * 4 + quad) * 4;  // write base (u32), 16B-aligned
    const float* xrow = &x_lds[l15 * XSTRIDE];

    const f32x4 vone  = {1.f, 1.f, 1.f, 1.f};
    const f32x4 vnC2  = {-C2, -C2, -C2, -C2};
    const f32x4 vC2   = {C2, C2, C2, C2};
    const f32x4 v40   = {40.f, 40.f, 40.f, 40.f};

    __syncthreads();

    // init for t=0 precomputed (x is h-independent): un-roots MFMA chain from x load
    f32x4 iv[4];
    {
        float xv = xrow[0];
        f32x4 xv4 = {xv, xv, xv, xv};
        #pragma unroll
        for (int g = 0; g < 4; ++g)
            iv[g] = __builtin_elementwise_fma(wih4[g], xv4, bias4[g]);
    }

    #pragma unroll 2
    for (int t = 0; t < T_STEPS; ++t) {
        const int rb = t & 1, wb = rb ^ 1;
        const short* hb = &hbuf[rb][0][0];

        // 4 B-fragments (virtual-K groups m=0..3) + next-step x
        bf16x8 bm0 = *reinterpret_cast<const bf16x8*>(hb + hoff);
        bf16x8 bm1 = *reinterpret_cast<const bf16x8*>(hb + hoff + 32);
        bf16x8 bm2 = *reinterpret_cast<const bf16x8*>(hb + hoff + 64);
        bf16x8 bm3 = *reinterpret_cast<const bf16x8*>(hb + hoff + 96);
        float xn = xrow[t + 1];   // t=511 reads in-bounds pad; result unused

        // 16 MFMAs, grouped by m: 4 independent chains (one per gate), depth 4
        f32x4 acc[4];
        #pragma unroll
        for (int g = 0; g < 4; ++g)
            acc[g] = __builtin_amdgcn_mfma_f32_16x16x32_bf16(Wv[g][0], bm0, iv[g], 0, 0, 0);
        #pragma unroll
        for (int g = 0; g < 4; ++g)
            acc[g] = __builtin_amdgcn_mfma_f32_16x16x32_bf16(Wv[g][1], bm1, acc[g], 0, 0, 0);
        #pragma unroll
        for (int g = 0; g < 4; ++g)
            acc[g] = __builtin_amdgcn_mfma_f32_16x16x32_bf16(Wv[g][2], bm2, acc[g], 0, 0, 0);
        #pragma unroll
        for (int g = 0; g < 4; ++g)
            acc[g] = __builtin_amdgcn_mfma_f32_16x16x32_bf16(Wv[g][3], bm3, acc[g], 0, 0, 0);

        // next-step iv prefetch issues in the MFMA-latency shadow (packed fp32)
        {
            f32x4 xn4 = {xn, xn, xn, xn};
            #pragma unroll
            for (int g = 0; g < 4; ++g)
                iv[g] = __builtin_elementwise_fma(wih4[g], xn4, bias4[g]);
        }

        // activations in scaled domain, vectorized f32x4.
        // signed-eg (safe range); clamped signed-ec (exact saturation).
        f32x4 ei, ef, eg, eo;
        #pragma unroll
        for (int r = 0; r < 4; ++r) {
            ei[r] = exp2_fast(acc[0][r]);
            ef[r] = exp2_fast(acc[1][r]);
            eg[r] = exp2_fast(acc[2][r]);
            eo[r] = exp2_fast(acc[3][r]);
        }
        f32x4 Ai = vone + ei, Af = vone + ef, Ag = vone + eg, Ao = vone + eo;
        f32x4 P   = Ai * Ag;
        f32x4 PAF = P * Af;
        f32x4 rP;
        #pragma unroll
        for (int r = 0; r < 4; ++r) rP[r] = __builtin_amdgcn_rcpf(PAF[r]);
        f32x4 tg  = __builtin_elementwise_fma(vnC2, eg, vC2);   // C2*(1-eg), sign built in
        f32x4 num = __builtin_elementwise_fma(ct4, P, tg * Af);
        f32x4 cn  = num * rP;                                   // scaled cell state
        ct4 = cn;
        f32x4 mm = __builtin_elementwise_min(-cn, v40);         // exp2 arg, clamped (safe)
        f32x4 ec;
        #pragma unroll
        for (int r = 0; r < 4; ++r) ec[r] = exp2_fast(mm[r]);
        f32x4 tc  = vone - ec;                                  // sign built in
        f32x4 den = Ao * (vone + ec);
        f32x4 rden;
        #pragma unroll
        for (int r = 0; r < 4; ++r) rden[r] = __builtin_amdgcn_rcpf(den[r]);
        f32x4 hv = tc * rden;                                   // real-unit h

        // bf16 pack (HW RNE) + exact lo residuals; ONE ds_write_b128 per lane:
        // [hi01, hi23, lo01, lo23] = 8 shorts = this lane's k-quad block
        unsigned hi01, hi23, lo01, lo23;
        asm("v_cvt_pk_bf16_f32 %0, %1, %2" : "=v"(hi01) : "v"(hv[0]), "v"(hv[1]));
        asm("v_cvt_pk_bf16_f32 %0, %1, %2" : "=v"(hi23) : "v"(hv[2]), "v"(hv[3]));
        f32x4 hif = { ubits(hi01 << 16), ubits(hi01 & 0xffff0000u),
                      ubits(hi23 << 16), ubits(hi23 & 0xffff0000u) };
        f32x4 l4 = hv - hif;   // exact residuals (Sterbenz)
        asm("v_cvt_pk_bf16_f32 %0, %1, %2" : "=v"(lo01) : "v"(l4[0]), "v"(l4[1]));
        asm("v_cvt_pk_bf16_f32 %0, %1, %2" : "=v"(lo23) : "v"(l4[2]), "v"(l4[3]));
        u32x4 hw = { hi01, hi23, lo01, lo23 };
        *reinterpret_cast<u32x4*>(reinterpret_cast<unsigned*>(&hbuf[wb][0][0]) + w32) = hw;

        __syncthreads();   // h(t+1) visible; also protects next step's overwrite of rb
    }

    // ---- final FC: out[b] = sum_k h[b][k]*W_fc[k] + b_fc  (h = buf 0 after t=511) ----
    if (tid < 16) {
        int b = tid;
        float s = b_fc[0];
        #pragma unroll 4
        for (int k = 0; k < 64; ++k) {
            int blk = k >> 2, j = k & 3;
            float hv = bf2f(hbuf[0][b][blk * 8 + j]) + bf2f(hbuf[0][b][blk * 8 + 4 + j]);
            s += hv * W_fc[k];
        }
        out[b0 + b] = s;
    }
}

extern "C" void kernel_launch(void* const* d_in, const int* in_sizes, int n_in,
                              void* d_out, int out_size, void* d_ws, size_t ws_size,
                              hipStream_t stream) {
    const float* x    = (const float*)d_in[0];
    const float* W_ih = (const float*)d_in[1];
    const float* W_hh = (const float*)d_in[2];
    const float* b_ih = (const float*)d_in[3];
    const float* b_hh = (const float*)d_in[4];
    const float* W_fc = (const float*)d_in[5];
    const float* b_fc = (const float*)d_in[6];
    float* out = (float*)d_out;
    const int B = in_sizes[0] / T_STEPS;   // 4096
    lstm_persist<<<dim3(B / BT), dim3(256), 0, stream>>>(
        x, W_ih, W_hh, b_ih, b_hh, W_fc, b_fc, out);
}

// Round 8
// 313.060 us; speedup vs baseline: 1.4658x; 1.0813x over previous
//
#include <hip/hip_runtime.h>

#define T_STEPS 512
#define BT 16          // batches per block (one 16-col MFMA tile, batch = l15)
#define XSTRIDE 524    // padded x row stride (floats); 2096B rows, 16B aligned
#define HS2 136        // shorts per h row: 128 virtual-K slots + 8 pad (272B, 16B-aligned)

typedef __attribute__((ext_vector_type(8))) short bf16x8;
typedef __attribute__((ext_vector_type(4))) float f32x4;
typedef __attribute__((ext_vector_type(4))) unsigned u32x4;

__device__ __forceinline__ short f2bf(float f) {
    union { float f; unsigned u; } v; v.f = f;
    unsigned r = v.u + 0x7fffu + ((v.u >> 16) & 1u);   // RNE
    return (short)(r >> 16);
}
__device__ __forceinline__ float bf2f(short s) {
    union { float f; unsigned u; } v;
    v.u = ((unsigned)(unsigned short)s) << 16;
    return v.f;
}
__device__ __forceinline__ float ubits(unsigned u) {
    union { unsigned u; float f; } v; v.u = u; return v.f;
}
__device__ __forceinline__ float exp2_fast(float x) {
#if __has_builtin(__builtin_amdgcn_exp2f)
    return __builtin_amdgcn_exp2f(x);
#else
    return __expf(x * 0.69314718056f);
#endif
}

#define L2E 1.44269504089f   // log2(e)
#define C2  2.88539008178f   // 2*log2(e)

__global__ __launch_bounds__(256, 1) void lstm_persist(
    const float* __restrict__ x,      // [B, T] (IN=1 folded)
    const float* __restrict__ W_ih,   // [256]
    const float* __restrict__ W_hh,   // [256,64]
    const float* __restrict__ b_ih,   // [256]
    const float* __restrict__ b_hh,   // [256]
    const float* __restrict__ W_fc,   // [64]
    const float* __restrict__ b_fc,   // [1]
    float* __restrict__ out)          // [B]
{
    __shared__ __align__(16) float x_lds[BT * XSTRIDE];    // 33.5 KB
    __shared__ __align__(16) short hbuf[2][BT][HS2];       // 8.7 KB, [hi x4 | lo x4] per k-quad

    const int tid  = threadIdx.x;
    const int wave = tid >> 6;     // 0..3
    const int lane = tid & 63;
    const int l15  = lane & 15;    // batch index (output col)
    const int quad = lane >> 4;    // 0..3
    const int b0   = blockIdx.x * BT;

    // ---- stage x[b0..b0+15][0..511] into LDS (coalesced float4) ----
    {
        const float* xg = x + (size_t)b0 * T_STEPS;
        #pragma unroll
        for (int i = 0; i < 8; ++i) {
            int f4 = tid + i * 256;        // 0..2047 float4 chunks
            int b  = f4 >> 7;              // 128 float4 per row
            int t4 = f4 & 127;
            float4 v = reinterpret_cast<const float4*>(xg + (size_t)b * T_STEPS)[t4];
            reinterpret_cast<float4*>(&x_lds[b * XSTRIDE + t4 * 4])[0] = v;
        }
    }
    // ---- zero h buffer 0 + the x pad (pad read at loop end feeds a dead iv) ----
    {
        short* p = &hbuf[0][0][0];
        for (int i = tid; i < BT * HS2; i += 256) p[i] = 0;
        if (tid < BT) x_lds[tid * XSTRIDE + 512] = 0.f;    // xq-next pad word
        if (tid >= 256 - 3 * BT && tid < 256) {            // pad words 513..515
            int b = (tid - (256 - 3 * BT)) / 3, j = (tid - (256 - 3 * BT)) % 3;
            x_lds[b * XSTRIDE + 513 + j] = 0.f;
        }
    }

    // ---- per-lane resident W fragments: duplicated-Whi virtual-K, ROTATED m-order ----
    // Wv[g][j] holds the fragment for real m = (wave+j)&3, so the MFMA chain starts at
    // m = wave (the self-produced fragment, kept in registers -> no ds_read, issues
    // inside the other reads' latency window). Gate scales folded in.
    const float scg[4] = { -L2E, -L2E, -C2, -L2E };
    bf16x8 Wv[4][4];               // [gate][j], j rotated
    f32x4 bias4[4], wih4[4];
    #pragma unroll
    for (int g = 0; g < 4; ++g) {
        int na = g * 64 + wave * 16 + l15;
        #pragma unroll
        for (int j = 0; j < 4; ++j) {
            int m = (wave + j) & 3;
            const float* wr = W_hh + na * 64 + m * 16 + quad * 4;
            bf16x8 a;
            #pragma unroll
            for (int jj = 0; jj < 4; ++jj) {
                short h16 = f2bf(wr[jj] * scg[g]);
                a[jj]     = h16;
                a[jj + 4] = h16;
            }
            Wv[g][j] = a;
        }
        #pragma unroll
        for (int r = 0; r < 4; ++r) {
            int n = g * 64 + wave * 16 + quad * 4 + r;
            bias4[g][r] = scg[g] * (b_ih[n] + b_hh[n]);
            wih4[g][r]  = scg[g] * W_ih[n];
        }
    }

    f32x4 ct4 = {0.f, 0.f, 0.f, 0.f};   // cell state, scaled by 2*log2e
    const int hoff = l15 * HS2 + quad * 8;                     // B-frag base (shorts)
    const int off1 = hoff + 32 * ((wave + 1) & 3);
    const int off2 = hoff + 32 * ((wave + 2) & 3);
    const int off3 = hoff + 32 * ((wave + 3) & 3);
    const int w32  = l15 * (HS2 / 2) + (wave * 4 + quad) * 4;  // write base (u32), 16B-aligned
    const f32x4* xrow4 = reinterpret_cast<const f32x4*>(&x_lds[l15 * XSTRIDE]);

    const f32x4 vone  = {1.f, 1.f, 1.f, 1.f};
    const f32x4 vnC2  = {-C2, -C2, -C2, -C2};
    const f32x4 vC2   = {C2, C2, C2, C2};
    const f32x4 v40   = {40.f, 40.f, 40.f, 40.f};

    u32x4 hw = {0u, 0u, 0u, 0u};   // self-written h block; h(0)=0 matches zeroed LDS

    __syncthreads();

    f32x4 xq = xrow4[0];           // x[t=0..3] for this lane's batch
    f32x4 iv[4];
    {
        f32x4 xv4 = {xq[0], xq[0], xq[0], xq[0]};
        #pragma unroll
        for (int g = 0; g < 4; ++g)
            iv[g] = __builtin_elementwise_fma(wih4[g], xv4, bias4[g]);
    }

    for (int tg = 0; tg < T_STEPS / 4; ++tg) {
        f32x4 xqn = xrow4[tg + 1];     // x[t+4..t+7]; tg=127 reads zeroed pad (dead iv)
        #pragma unroll
        for (int u = 0; u < 4; ++u) {
            const int rb = u & 1, wb = rb ^ 1;     // compile-time buffer parity
            const short* hb = &hbuf[rb][0][0];

            // 3 ds_reads (m != wave); self fragment comes from registers
            bf16x8 b1 = *reinterpret_cast<const bf16x8*>(hb + off1);
            bf16x8 b2 = *reinterpret_cast<const bf16x8*>(hb + off2);
            bf16x8 b3 = *reinterpret_cast<const bf16x8*>(hb + off3);
            bf16x8 bself;
            __builtin_memcpy(&bself, &hw, 16);     // bit-identical to LDS round-trip

            // 16 MFMAs; self chainlet first (issues during ds_read latency)
            f32x4 acc[4];
            #pragma unroll
            for (int g = 0; g < 4; ++g)
                acc[g] = __builtin_amdgcn_mfma_f32_16x16x32_bf16(Wv[g][0], bself, iv[g], 0, 0, 0);
            #pragma unroll
            for (int g = 0; g < 4; ++g)
                acc[g] = __builtin_amdgcn_mfma_f32_16x16x32_bf16(Wv[g][1], b1, acc[g], 0, 0, 0);
            #pragma unroll
            for (int g = 0; g < 4; ++g)
                acc[g] = __builtin_amdgcn_mfma_f32_16x16x32_bf16(Wv[g][2], b2, acc[g], 0, 0, 0);
            #pragma unroll
            for (int g = 0; g < 4; ++g)
                acc[g] = __builtin_amdgcn_mfma_f32_16x16x32_bf16(Wv[g][3], b3, acc[g], 0, 0, 0);

            // next-step iv prefetch in the MFMA-latency shadow (x from registers)
            {
                float xn = (u < 3) ? xq[u + 1] : xqn[0];
                f32x4 xn4 = {xn, xn, xn, xn};
                #pragma unroll
                for (int g = 0; g < 4; ++g)
                    iv[g] = __builtin_elementwise_fma(wih4[g], xn4, bias4[g]);
            }

            // activations in scaled domain, vectorized f32x4.
            f32x4 ei, ef, eg, eo;
            #pragma unroll
            for (int r = 0; r < 4; ++r) {
                ei[r] = exp2_fast(acc[0][r]);
                ef[r] = exp2_fast(acc[1][r]);
                eg[r] = exp2_fast(acc[2][r]);
                eo[r] = exp2_fast(acc[3][r]);
            }
            f32x4 Ai = vone + ei, Af = vone + ef, Ag = vone + eg, Ao = vone + eo;
            f32x4 P   = Ai * Ag;
            f32x4 PAF = P * Af;
            f32x4 rP;
            #pragma unroll
            for (int r = 0; r < 4; ++r) rP[r] = __builtin_amdgcn_rcpf(PAF[r]);
            f32x4 tg4 = __builtin_elementwise_fma(vnC2, eg, vC2);   // C2*(1-eg), signed
            f32x4 num = __builtin_elementwise_fma(ct4, P, tg4 * Af);
            f32x4 cn  = num * rP;                                   // scaled cell state
            ct4 = cn;
            f32x4 mm = __builtin_elementwise_min(-cn, v40);         // exp2 arg, clamped
            f32x4 ec;
            #pragma unroll
            for (int r = 0; r < 4; ++r) ec[r] = exp2_fast(mm[r]);
            f32x4 tc  = vone - ec;
            f32x4 den = Ao * (vone + ec);
            f32x4 rden;
            #pragma unroll
            for (int r = 0; r < 4; ++r) rden[r] = __builtin_amdgcn_rcpf(den[r]);
            f32x4 hv = tc * rden;                                   // real-unit h

            // bf16 pack (HW RNE) + exact lo residuals; ONE ds_write_b128, kept in hw
            unsigned hi01, hi23, lo01, lo23;
            asm("v_cvt_pk_bf16_f32 %0, %1, %2" : "=v"(hi01) : "v"(hv[0]), "v"(hv[1]));
            asm("v_cvt_pk_bf16_f32 %0, %1, %2" : "=v"(hi23) : "v"(hv[2]), "v"(hv[3]));
            f32x4 hif = { ubits(hi01 << 16), ubits(hi01 & 0xffff0000u),
                          ubits(hi23 << 16), ubits(hi23 & 0xffff0000u) };
            f32x4 l4 = hv - hif;   // exact residuals (Sterbenz)
            asm("v_cvt_pk_bf16_f32 %0, %1, %2" : "=v"(lo01) : "v"(l4[0]), "v"(l4[1]));
            asm("v_cvt_pk_bf16_f32 %0, %1, %2" : "=v"(lo23) : "v"(l4[2]), "v"(l4[3]));
            hw = (u32x4){ hi01, hi23, lo01, lo23 };
            *reinterpret_cast<u32x4*>(reinterpret_cast<unsigned*>(&hbuf[wb][0][0]) + w32) = hw;

            __syncthreads();   // h(t+1) visible; protects next step's overwrite of rb
        }
        xq = xqn;
    }

    // ---- final FC: out[b] = sum_k h[b][k]*W_fc[k] + b_fc  (h = buf 0 after t=511) ----
    if (tid < 16) {
        int b = tid;
        float s = b_fc[0];
        #pragma unroll 4
        for (int k = 0; k < 64; ++k) {
            int blk = k >> 2, j = k & 3;
            float hv = bf2f(hbuf[0][b][blk * 8 + j]) + bf2f(hbuf[0][b][blk * 8 + 4 + j]);
            s += hv * W_fc[k];
        }
        out[b0 + b] = s;
    }
}

extern "C" void kernel_launch(void* const* d_in, const int* in_sizes, int n_in,
                              void* d_out, int out_size, void* d_ws, size_t ws_size,
                              hipStream_t stream) {
    const float* x    = (const float*)d_in[0];
    const float* W_ih = (const float*)d_in[1];
    const float* W_hh = (const float*)d_in[2];
    const float* b_ih = (const float*)d_in[3];
    const float* b_hh = (const float*)d_in[4];
    const float* W_fc = (const float*)d_in[5];
    const float* b_fc = (const float*)d_in[6];
    float* out = (float*)d_out;
    const int B = in_sizes[0] / T_STEPS;   // 4096
    lstm_persist<<<dim3(B / BT), dim3(256), 0, stream>>>(
        x, W_ih, W_hh, b_ih, b_hh, W_fc, b_fc, out);
}

// Round 9
// 268.233 us; speedup vs baseline: 1.7108x; 1.1671x over previous
//
#include <hip/hip_runtime.h>

#define T_STEPS 512
#define BT 16          // batches per block (one 16-col MFMA tile, batch = l15)
#define XSTRIDE 524    // padded x row stride (floats); 2096B rows, 16B aligned
#define HSTRIDE 72     // f16 per h row: 64 + 8 pad (144B rows, 16B aligned)

typedef __attribute__((ext_vector_type(8))) _Float16 f16x8;
typedef __attribute__((ext_vector_type(4))) _Float16 f16x4;
typedef __attribute__((ext_vector_type(4))) float f32x4;

__device__ __forceinline__ float ubits(unsigned u) {
    union { unsigned u; float f; } v; v.u = u; return v.f;
}
__device__ __forceinline__ float exp2_fast(float x) {
#if __has_builtin(__builtin_amdgcn_exp2f)
    return __builtin_amdgcn_exp2f(x);
#else
    return __expf(x * 0.69314718056f);
#endif
}

#define L2E 1.44269504089f   // log2(e)
#define C2  2.88539008178f   // 2*log2(e)

__global__ __launch_bounds__(256, 1) void lstm_persist(
    const float* __restrict__ x,      // [B, T] (IN=1 folded)
    const float* __restrict__ W_ih,   // [256]
    const float* __restrict__ W_hh,   // [256,64]
    const float* __restrict__ b_ih,   // [256]
    const float* __restrict__ b_hh,   // [256]
    const float* __restrict__ W_fc,   // [64]
    const float* __restrict__ b_fc,   // [1]
    float* __restrict__ out)          // [B]
{
    __shared__ __align__(16) float x_lds[BT * XSTRIDE];      // 33.5 KB
    __shared__ __align__(16) _Float16 hbuf[2][BT][HSTRIDE];  // 4.6 KB, h as plain f16

    const int tid  = threadIdx.x;
    const int wave = tid >> 6;     // 0..3  -> k-slice: k in [16w, 16w+16)
    const int lane = tid & 63;
    const int l15  = lane & 15;    // batch index (output col)
    const int quad = lane >> 4;    // 0..3
    const int b0   = blockIdx.x * BT;

    // ---- stage x[b0..b0+15][0..511] into LDS (coalesced float4) ----
    {
        const float* xg = x + (size_t)b0 * T_STEPS;
        #pragma unroll
        for (int i = 0; i < 8; ++i) {
            int f4 = tid + i * 256;        // 0..2047 float4 chunks
            int b  = f4 >> 7;              // 128 float4 per row
            int t4 = f4 & 127;
            float4 v = reinterpret_cast<const float4*>(xg + (size_t)b * T_STEPS)[t4];
            reinterpret_cast<float4*>(&x_lds[b * XSTRIDE + t4 * 4])[0] = v;
        }
    }
    // ---- zero h buffer 0 + x pad words (pad feeds a dead iv at loop end) ----
    {
        _Float16* p = &hbuf[0][0][0];
        for (int i = tid; i < BT * HSTRIDE; i += 256) p[i] = (_Float16)0.f;
        if (tid < BT) {
            x_lds[tid * XSTRIDE + 512] = 0.f;
            x_lds[tid * XSTRIDE + 513] = 0.f;
            x_lds[tid * XSTRIDE + 514] = 0.f;
            x_lds[tid * XSTRIDE + 515] = 0.f;
        }
    }

    // ---- per-lane resident W_hh fragments (f16, RNE, scaled) ----
    // Gate scales folded in: i,f,o rows by -log2e; g rows by -2*log2e.
    // A-frag (K=32, group m): lane holds A[m=l15][k=quad*8+j] = W'[row][m*32+quad*8+j].
    const float scg[4] = { -L2E, -L2E, -C2, -L2E };
    f16x8 Wf[4][2];                // [gate][m]
    f32x4 bias4[4], wih4[4];
    #pragma unroll
    for (int g = 0; g < 4; ++g) {
        int na = g * 64 + wave * 16 + l15;
        #pragma unroll
        for (int m = 0; m < 2; ++m) {
            const float* wr = W_hh + na * 64 + m * 32 + quad * 8;
            f16x8 a;
            #pragma unroll
            for (int j = 0; j < 8; ++j) a[j] = (_Float16)(wr[j] * scg[g]);  // RNE cvt
            Wf[g][m] = a;
        }
        // D layout: col = l15 (batch), row = quad*4 + r ->
        // lane owns gate g, k_hidden = wave*16 + quad*4 + r, batch l15.
        #pragma unroll
        for (int r = 0; r < 4; ++r) {
            int n = g * 64 + wave * 16 + quad * 4 + r;
            bias4[g][r] = scg[g] * (b_ih[n] + b_hh[n]);
            wih4[g][r]  = scg[g] * W_ih[n];
        }
    }

    f32x4 ct4 = {0.f, 0.f, 0.f, 0.f};   // cell state, scaled by 2*log2e
    const int hoff = l15 * HSTRIDE + quad * 8;            // B-frag base (f16), +32 for m=1
    const int wofs = l15 * HSTRIDE + wave * 16 + quad * 4; // write base (f16), 8B-aligned
    const f32x4* xrow4 = reinterpret_cast<const f32x4*>(&x_lds[l15 * XSTRIDE]);

    const f32x4 vone  = {1.f, 1.f, 1.f, 1.f};
    const f32x4 vnC2  = {-C2, -C2, -C2, -C2};
    const f32x4 vC2   = {C2, C2, C2, C2};
    const f32x4 v40   = {40.f, 40.f, 40.f, 40.f};

    __syncthreads();

    f32x4 xq = xrow4[0];           // x[t=0..3] for this lane's batch
    f32x4 iv[4];
    {
        f32x4 xv4 = {xq[0], xq[0], xq[0], xq[0]};
        #pragma unroll
        for (int g = 0; g < 4; ++g)
            iv[g] = __builtin_elementwise_fma(wih4[g], xv4, bias4[g]);
    }

    for (int tg = 0; tg < T_STEPS / 4; ++tg) {
        f32x4 xqn = xrow4[tg + 1];     // x[t+4..t+7]; tg=127 reads zeroed pad (dead iv)
        #pragma unroll
        for (int u = 0; u < 4; ++u) {
            const int rb = u & 1, wb = rb ^ 1;     // compile-time buffer parity
            const _Float16* hb = &hbuf[rb][0][0];

            // 2 ds_read_b128: B-fragments for K-groups m=0,1
            f16x8 bm0 = *reinterpret_cast<const f16x8*>(hb + hoff);
            f16x8 bm1 = *reinterpret_cast<const f16x8*>(hb + hoff + 32);

            // 8 MFMAs: 4 parallel gate-chains, depth 2
            f32x4 acc[4];
            #pragma unroll
            for (int g = 0; g < 4; ++g)
                acc[g] = __builtin_amdgcn_mfma_f32_16x16x32_f16(Wf[g][0], bm0, iv[g], 0, 0, 0);
            #pragma unroll
            for (int g = 0; g < 4; ++g)
                acc[g] = __builtin_amdgcn_mfma_f32_16x16x32_f16(Wf[g][1], bm1, acc[g], 0, 0, 0);

            // next-step iv prefetch in the MFMA-latency shadow (x from registers)
            {
                float xn = (u < 3) ? xq[u + 1] : xqn[0];
                f32x4 xn4 = {xn, xn, xn, xn};
                #pragma unroll
                for (int g = 0; g < 4; ++g)
                    iv[g] = __builtin_elementwise_fma(wih4[g], xn4, bias4[g]);
            }

            // activations in scaled domain, vectorized f32x4 (acc IS the exp2 arg)
            f32x4 ei, ef, eg, eo;
            #pragma unroll
            for (int r = 0; r < 4; ++r) {
                ei[r] = exp2_fast(acc[0][r]);
                ef[r] = exp2_fast(acc[1][r]);
                eg[r] = exp2_fast(acc[2][r]);
                eo[r] = exp2_fast(acc[3][r]);
            }
            f32x4 Ai = vone + ei, Af = vone + ef, Ag = vone + eg, Ao = vone + eo;
            f32x4 P   = Ai * Ag;
            f32x4 PAF = P * Af;
            f32x4 rP;
            #pragma unroll
            for (int r = 0; r < 4; ++r) rP[r] = __builtin_amdgcn_rcpf(PAF[r]);
            f32x4 tg4 = __builtin_elementwise_fma(vnC2, eg, vC2);   // C2*(1-eg), signed
            f32x4 num = __builtin_elementwise_fma(ct4, P, tg4 * Af);
            f32x4 cn  = num * rP;                                   // scaled cell state
            ct4 = cn;
            f32x4 mm = __builtin_elementwise_min(-cn, v40);         // exp2 arg, clamped
            f32x4 ec;
            #pragma unroll
            for (int r = 0; r < 4; ++r) ec[r] = exp2_fast(mm[r]);
            f32x4 tc  = vone - ec;
            f32x4 den = Ao * (vone + ec);
            f32x4 rden;
            #pragma unroll
            for (int r = 0; r < 4; ++r) rden[r] = __builtin_amdgcn_rcpf(den[r]);
            f32x4 hv = tc * rden;                                   // real-unit h

            // f16 pack (RNE via v_cvt_f16_f32) + ONE ds_write_b64 per lane
            f16x4 h16 = { (_Float16)hv[0], (_Float16)hv[1],
                          (_Float16)hv[2], (_Float16)hv[3] };
            *reinterpret_cast<f16x4*>(&hbuf[wb][0][0] + wofs) = h16;

            __syncthreads();   // h(t+1) visible; protects next step's overwrite of rb
        }
        xq = xqn;
    }

    // ---- final FC: out[b] = sum_k h[b][k]*W_fc[k] + b_fc  (h = buf 0 after t=511) ----
    if (tid < 16) {
        int b = tid;
        float s = b_fc[0];
        #pragma unroll 4
        for (int k = 0; k < 64; ++k) {
            s += (float)hbuf[0][b][k] * W_fc[k];
        }
        out[b0 + b] = s;
    }
}

extern "C" void kernel_launch(void* const* d_in, const int* in_sizes, int n_in,
                              void* d_out, int out_size, void* d_ws, size_t ws_size,
                              hipStream_t stream) {
    const float* x    = (const float*)d_in[0];
    const float* W_ih = (const float*)d_in[1];
    const float* W_hh = (const float*)d_in[2];
    const float* b_ih = (const float*)d_in[3];
    const float* b_hh = (const float*)d_in[4];
    const float* W_fc = (const float*)d_in[5];
    const float* b_fc = (const float*)d_in[6];
    float* out = (float*)d_out;
    const int B = in_sizes[0] / T_STEPS;   // 4096
    lstm_persist<<<dim3(B / BT), dim3(256), 0, stream>>>(
        x, W_ih, W_hh, b_ih, b_hh, W_fc, b_fc, out);
}

// Round 10
// 261.626 us; speedup vs baseline: 1.7540x; 1.0253x over previous
//
#include <hip/hip_runtime.h>

#define T_STEPS 512
#define BT 16          // batches per block (one 16-col MFMA tile, batch = l15)
#define XSTRIDE 524    // padded x row stride (floats); 2096B rows, 16B aligned
#define HSTRIDE 72     // f16 per h row: 64 + 8 pad (144B rows, 16B aligned)

typedef __attribute__((ext_vector_type(8))) _Float16 f16x8;
typedef __attribute__((ext_vector_type(4))) _Float16 f16x4;
typedef __attribute__((ext_vector_type(4))) float f32x4;

__device__ __forceinline__ float exp2_fast(float x) {
#if __has_builtin(__builtin_amdgcn_exp2f)
    return __builtin_amdgcn_exp2f(x);
#else
    return __expf(x * 0.69314718056f);
#endif
}

#define L2E 1.44269504089f   // log2(e)
#define C2  2.88539008178f   // 2*log2(e)

__global__ __launch_bounds__(256, 1) void lstm_persist(
    const float* __restrict__ x,      // [B, T] (IN=1 folded)
    const float* __restrict__ W_ih,   // [256]
    const float* __restrict__ W_hh,   // [256,64]
    const float* __restrict__ b_ih,   // [256]
    const float* __restrict__ b_hh,   // [256]
    const float* __restrict__ W_fc,   // [64]
    const float* __restrict__ b_fc,   // [1]
    float* __restrict__ out)          // [B]
{
    __shared__ __align__(16) float x_lds[BT * XSTRIDE];      // 33.5 KB
    __shared__ __align__(16) _Float16 hbuf[2][BT][HSTRIDE];  // 4.6 KB, h as plain f16

    const int tid  = threadIdx.x;
    const int wave = tid >> 6;     // 0..3  -> k-slice: k in [16w, 16w+16)
    const int lane = tid & 63;
    const int l15  = lane & 15;    // batch index (output col)
    const int quad = lane >> 4;    // 0..3
    const int b0   = blockIdx.x * BT;

    // ---- stage x[b0..b0+15][0..511] into LDS (coalesced float4) ----
    {
        const float* xg = x + (size_t)b0 * T_STEPS;
        #pragma unroll
        for (int i = 0; i < 8; ++i) {
            int f4 = tid + i * 256;        // 0..2047 float4 chunks
            int b  = f4 >> 7;              // 128 float4 per row
            int t4 = f4 & 127;
            float4 v = reinterpret_cast<const float4*>(xg + (size_t)b * T_STEPS)[t4];
            reinterpret_cast<float4*>(&x_lds[b * XSTRIDE + t4 * 4])[0] = v;
        }
    }
    // ---- zero h buffer 0 + x pad words (pad feeds a dead iv at loop end) ----
    {
        _Float16* p = &hbuf[0][0][0];
        for (int i = tid; i < BT * HSTRIDE; i += 256) p[i] = (_Float16)0.f;
        if (tid < BT) {
            x_lds[tid * XSTRIDE + 512] = 0.f;
            x_lds[tid * XSTRIDE + 513] = 0.f;
            x_lds[tid * XSTRIDE + 514] = 0.f;
            x_lds[tid * XSTRIDE + 515] = 0.f;
        }
    }

    // ---- per-lane resident W_hh fragments (f16, RNE, scaled) ----
    // Gate scales folded in: i,f,o rows by -log2e; g rows by -2*log2e.
    // A-frag (K=32, group m): lane holds A[m=l15][k=quad*8+j] = W'[row][m*32+quad*8+j].
    const float scg[4] = { -L2E, -L2E, -C2, -L2E };
    f16x8 Wf[4][2];                // [gate][m]
    f32x4 bias4[4], wih4[4];
    #pragma unroll
    for (int g = 0; g < 4; ++g) {
        int na = g * 64 + wave * 16 + l15;
        #pragma unroll
        for (int m = 0; m < 2; ++m) {
            const float* wr = W_hh + na * 64 + m * 32 + quad * 8;
            f16x8 a;
            #pragma unroll
            for (int j = 0; j < 8; ++j) a[j] = (_Float16)(wr[j] * scg[g]);  // RNE cvt
            Wf[g][m] = a;
        }
        // D layout: col = l15 (batch), row = quad*4 + r ->
        // lane owns gate g, k_hidden = wave*16 + quad*4 + r, batch l15.
        #pragma unroll
        for (int r = 0; r < 4; ++r) {
            int n = g * 64 + wave * 16 + quad * 4 + r;
            bias4[g][r] = scg[g] * (b_ih[n] + b_hh[n]);
            wih4[g][r]  = scg[g] * W_ih[n];
        }
    }

    f32x4 ct4 = {0.f, 0.f, 0.f, 0.f};   // cell state, scaled by 2*log2e
    const int hoff = l15 * HSTRIDE + quad * 8;            // B-frag base (f16), +32 for m=1
    const int wofs = l15 * HSTRIDE + wave * 16 + quad * 4; // write base (f16), 8B-aligned
    const f32x4* xrow4 = reinterpret_cast<const f32x4*>(&x_lds[l15 * XSTRIDE]);

    const f32x4 vone  = {1.f, 1.f, 1.f, 1.f};
    const f32x4 vnC2  = {-C2, -C2, -C2, -C2};
    const f32x4 vC2   = {C2, C2, C2, C2};
    const f32x4 vn40  = {-40.f, -40.f, -40.f, -40.f};

    __syncthreads();

    f32x4 xq = xrow4[0];           // x[t=0..3] for this lane's batch
    f32x4 iv[4];
    {
        f32x4 xv4 = {xq[0], xq[0], xq[0], xq[0]};
        #pragma unroll
        for (int g = 0; g < 4; ++g)
            iv[g] = __builtin_elementwise_fma(wih4[g], xv4, bias4[g]);
    }

    #pragma unroll 2
    for (int tg = 0; tg < T_STEPS / 4; ++tg) {
        f32x4 xqn = xrow4[tg + 1];     // x[t+4..t+7]; tg=127 reads zeroed pad (dead iv)
        #pragma unroll
        for (int u = 0; u < 4; ++u) {
            const int rb = u & 1, wb = rb ^ 1;     // compile-time buffer parity
            const _Float16* hb = &hbuf[rb][0][0];

            // 2 ds_read_b128: B-fragments for K-groups m=0,1
            f16x8 bm0 = *reinterpret_cast<const f16x8*>(hb + hoff);
            f16x8 bm1 = *reinterpret_cast<const f16x8*>(hb + hoff + 32);

            // 8 MFMAs: 4 parallel gate-chains, depth 2
            f32x4 acc[4];
            #pragma unroll
            for (int g = 0; g < 4; ++g)
                acc[g] = __builtin_amdgcn_mfma_f32_16x16x32_f16(Wf[g][0], bm0, iv[g], 0, 0, 0);
            #pragma unroll
            for (int g = 0; g < 4; ++g)
                acc[g] = __builtin_amdgcn_mfma_f32_16x16x32_f16(Wf[g][1], bm1, acc[g], 0, 0, 0);

            // next-step iv prefetch in the MFMA-latency shadow (x from registers)
            {
                float xn = (u < 3) ? xq[u + 1] : xqn[0];
                f32x4 xn4 = {xn, xn, xn, xn};
                #pragma unroll
                for (int g = 0; g < 4; ++g)
                    iv[g] = __builtin_elementwise_fma(wih4[g], xn4, bias4[g]);
            }

            // activations in scaled domain, vectorized f32x4 (acc IS the exp2 arg)
            f32x4 ei, ef, eg, eo;
            #pragma unroll
            for (int r = 0; r < 4; ++r) {
                ei[r] = exp2_fast(acc[0][r]);
                ef[r] = exp2_fast(acc[1][r]);
                eg[r] = exp2_fast(acc[2][r]);
                eo[r] = exp2_fast(acc[3][r]);
            }
            f32x4 Ai = vone + ei, Af = vone + ef, Ag = vone + eg, Ao = vone + eo;
            f32x4 P   = Ai * Ag;
            f32x4 PAF = P * Af;
            f32x4 rP;
            #pragma unroll
            for (int r = 0; r < 4; ++r) rP[r] = __builtin_amdgcn_rcpf(PAF[r]);
            f32x4 tg4 = __builtin_elementwise_fma(vnC2, eg, vC2);   // C2*(1-eg), signed
            f32x4 num = __builtin_elementwise_fma(ct4, P, tg4 * Af);
            f32x4 cn  = num * rP;                                   // scaled cell state
            ct4 = cn;
            // ec = exp2(min(-cn,40)) == exp2(-max(cn,-40)): neg folds into v_exp src mod
            f32x4 mx = __builtin_elementwise_max(cn, vn40);
            f32x4 ec;
            #pragma unroll
            for (int r = 0; r < 4; ++r) ec[r] = exp2_fast(-mx[r]);
            f32x4 tc  = vone - ec;
            f32x4 den = __builtin_elementwise_fma(Ao, ec, Ao);      // Ao*(1+ec), 1 pk op
            f32x4 rden;
            #pragma unroll
            for (int r = 0; r < 4; ++r) rden[r] = __builtin_amdgcn_rcpf(den[r]);
            f32x4 hv = tc * rden;                                   // real-unit h

            // f16 pack (RNE via v_cvt_f16_f32) + ONE ds_write_b64 per lane
            f16x4 h16 = { (_Float16)hv[0], (_Float16)hv[1],
                          (_Float16)hv[2], (_Float16)hv[3] };
            *reinterpret_cast<f16x4*>(&hbuf[wb][0][0] + wofs) = h16;

            __syncthreads();   // h(t+1) visible; protects next step's overwrite of rb
        }
        xq = xqn;
    }

    // ---- final FC: out[b] = sum_k h[b][k]*W_fc[k] + b_fc  (h = buf 0 after t=511) ----
    if (tid < 16) {
        int b = tid;
        float s = b_fc[0];
        #pragma unroll 4
        for (int k = 0; k < 64; ++k) {
            s += (float)hbuf[0][b][k] * W_fc[k];
        }
        out[b0 + b] = s;
    }
}

extern "C" void kernel_launch(void* const* d_in, const int* in_sizes, int n_in,
                              void* d_out, int out_size, void* d_ws, size_t ws_size,
                              hipStream_t stream) {
    const float* x    = (const float*)d_in[0];
    const float* W_ih = (const float*)d_in[1];
    const float* W_hh = (const float*)d_in[2];
    const float* b_ih = (const float*)d_in[3];
    const float* b_hh = (const float*)d_in[4];
    const float* W_fc = (const float*)d_in[5];
    const float* b_fc = (const float*)d_in[6];
    float* out = (float*)d_out;
    const int B = in_sizes[0] / T_STEPS;   // 4096
    lstm_persist<<<dim3(B / BT), dim3(256), 0, stream>>>(
        x, W_ih, W_hh, b_ih, b_hh, W_fc, b_fc, out);
}